// Round 23
// baseline (116.078 us; speedup 1.0000x reference)
//
#include <hip/hip_runtime.h>
#include <cstdint>
#include <cstddef>

#define DIMC    192
#define NHEADS  6
#define NATT    486
#define NB      16
#define NH      56
#define NWW     56
#define HPOOL   28
#define WPOOL   28
#define NPIX    784
#define VH      58
#define VW      58
#define MROWS   (NB*NH*NWW)      // 50176
#define MPOOL   (NB*NPIX)        // 12544
#define SCALE_A 0.17677669529663687f
#define AROW    10               // attn row stride (bf16 elems): 9 weights + 1 pad

using bf16x8 = __attribute__((ext_vector_type(8))) short;
using f32x4  = __attribute__((ext_vector_type(4))) float;
typedef short bf16x8u __attribute__((vector_size(16), aligned(4)));   // 16B load @4B align

static __device__ __forceinline__ unsigned short f2bf(float f) {
    unsigned int u = __float_as_uint(f);
    unsigned int r = (u + 0x7fffu + ((u >> 16) & 1u)) >> 16;   // RNE
    return (unsigned short)r;
}
static __device__ __forceinline__ float bf2f(unsigned short u) {
    return __uint_as_float((unsigned int)u << 16);
}

// async global->LDS, 16B per lane
static __device__ __forceinline__ void gload_lds16(const void* src, void* lds) {
    __builtin_amdgcn_global_load_lds(
        (const __attribute__((address_space(1))) void*)src,
        (__attribute__((address_space(3))) void*)lds, 16, 0, 0);
}

// =====================================================================
// Prep: WTv/WTp[n][k]=bf16(W[k][n]); WaT=bf16(Wa*SCALE); vp border=0.
// =====================================================================
__global__ __launch_bounds__(256)
void prep_kernel(const float* __restrict__ Wv, const float* __restrict__ Wp,
                 const float* __restrict__ Wa,
                 unsigned short* __restrict__ WTv, unsigned short* __restrict__ WTp,
                 unsigned short* __restrict__ WaT, unsigned int* __restrict__ vpu)
{
    int idx = blockIdx.x * 256 + threadIdx.x;
    if (idx < 73728) {
        int sel = idx / 36864;
        int r   = idx - sel * 36864;
        int n   = r / DIMC;
        int k   = r - n * DIMC;
        const float* W = sel ? Wp : Wv;
        unsigned short* WT = sel ? WTp : WTv;
        WT[r] = f2bf(W[k * DIMC + n]);
    } else if (idx < 172032) {
        int r = idx - 73728;
        int n = r / DIMC;
        int k = r - n * DIMC;
        WaT[r] = (n < NATT) ? f2bf(Wa[(size_t)k * NATT + n] * SCALE_A) : (unsigned short)0;
    } else {
        int i2   = idx - 172032;                  // 0..350207
        int cu   = i2 % 96;
        int rest = i2 / 96;
        int b    = rest / 228;
        int p    = rest - b * 228;
        int hi, wi;
        if (p < 58)       { hi = 0;  wi = p; }
        else if (p < 116) { hi = 57; wi = p - 58; }
        else { int q = p - 116; hi = 1 + (q >> 1); wi = (q & 1) * 57; }
        vpu[(((size_t)b * VH + hi) * VW + wi) * 96 + cu] = 0u;
    }
}

// =====================================================================
// GEMM0 body v2: BM=64, half-N (96 cols), 512 thr = 8 waves.
// NO A-staging LDS: each lane loads its MFMA A-fragment directly from
// global x (2x float4, 128B-granule coalesced) and converts in-register,
// issued BEFORE the Ws barrier so they overlap the gload_lds wait.
// Ws (36KB) is the only LDS -> 3 blocks/CU (VGPR-capped).
// Epilogue Cs reuses the Ws region (dead after K-loop).
// XCD+batch mapping as R22: xcd=(g+4)&7, rank=g>>3,
// tile=xcd*98+(rank>>1), half=rank&1.
// =====================================================================
static __device__ __forceinline__
void gemm0_body(const float* __restrict__ x, const unsigned short* __restrict__ WTv,
                unsigned short* __restrict__ vp, int g, int t, char* smem)
{
    unsigned short* Ws = (unsigned short*)smem;            // [0, 36864)

    const int xcd  = (g + 4) & 7;
    const int rank = g >> 3;               // 0..195 within this XCD
    const int tile = xcd * 98 + (rank >> 1);   // 0..783
    const int half = rank & 1;
    const int l  = t & 63;
    const int w  = t >> 6;
    const int wr = w >> 1;          // 0..3 : 16-row band
    const int wc = w & 1;           // 0..1 : 48-col half of the 96

    // ---- stage Ws: 96 WT rows (bf16) -> swizzled LDS, async ----
    const unsigned short* Wb = WTv + (size_t)half * 96 * DIMC;
#pragma unroll
    for (int i = 0; i < 5; ++i) {
        int L = i * 8192 + t * 16;
        if (L < 36864) {
            int row   = L / 384;
            int inrow = L - row * 384;
            int s     = (row & 7) << 4;
            const unsigned short* src = Wb + (size_t)row * DIMC + ((inrow ^ s) >> 1);
            gload_lds16(src, (char*)Ws + (L & ~1023) + ((t & 63) << 4));
        }
    }

    // ---- A fragments: direct global fp32 loads + in-register convert ----
    const int arow = wr * 16 + (l & 15);
    const int ke   = (l >> 4) * 8;        // elem offset within each 32-elem K-block
    const float* Arow = x + (size_t)(tile * 64 + arow) * DIMC + ke;

    bf16x8 afr[6];
#pragma unroll
    for (int ks = 0; ks < 6; ++ks) {
        float4 v0 = *(const float4*)(Arow + ks * 32);
        float4 v1 = *(const float4*)(Arow + ks * 32 + 4);
        bf16x8 a;
        a[0] = (short)f2bf(v0.x); a[1] = (short)f2bf(v0.y);
        a[2] = (short)f2bf(v0.z); a[3] = (short)f2bf(v0.w);
        a[4] = (short)f2bf(v1.x); a[5] = (short)f2bf(v1.y);
        a[6] = (short)f2bf(v1.z); a[7] = (short)f2bf(v1.w);
        afr[ks] = a;
    }

    __syncthreads();   // Ws ready (drains vmcnt)

    f32x4 acc[3];
#pragma unroll
    for (int ni = 0; ni < 3; ++ni) acc[ni] = (f32x4)0.f;

    const int kb = (l >> 4) << 4;

#pragma unroll
    for (int ks = 0; ks < 6; ++ks) {
        bf16x8 b[3];
#pragma unroll
        for (int ni = 0; ni < 3; ++ni) {
            int n = wc * 48 + ni * 16 + (l & 15);
            b[ni] = *(const bf16x8*)((const char*)Ws +
                        ((n * 384 + ks * 64 + kb) ^ ((n & 7) << 4)));
        }
#pragma unroll
        for (int ni = 0; ni < 3; ++ni)
            acc[ni] = __builtin_amdgcn_mfma_f32_16x16x32_bf16(afr[ks], b[ni], acc[ni], 0, 0, 0);
    }

    // ---- epilogue: 64x96 bf16 half-tile via LDS (reuse Ws region) ----
    __syncthreads();
    unsigned short* Cs = Ws;                   // [64][96] = 12 KB
#pragma unroll
    for (int ni = 0; ni < 3; ++ni) {
        int col = wc * 48 + ni * 16 + (l & 15);
#pragma unroll
        for (int r = 0; r < 4; ++r) {
            int row = wr * 16 + ((l >> 4) << 2) + r;
            Cs[row * 96 + col] = f2bf(acc[ni][r]);
        }
    }
    __syncthreads();
#pragma unroll
    for (int i = 0; i < 2; ++i) {
        int idx = i * 8192 + t * 16;           // byte offset in [0,12288)
        if (idx < 12288) {
            int row = idx / 192;
            int cb  = idx - row * 192;         // byte within row (96 cols * 2B)
            int m   = tile * 64 + row;
            int bb  = m / (NH * NWW);
            int rr  = m - bb * (NH * NWW);
            int hi  = rr / NWW;
            int wi  = rr - hi * NWW;
            bf16x8 v = *(const bf16x8*)((const char*)Cs + idx);
            unsigned short* dst = vp +
                (((size_t)bb * VH + hi + 1) * VW + (wi + 1)) * DIMC + half * 96 + (cb >> 1);
            *(bf16x8*)dst = v;
        }
    }
}

// =====================================================================
// pool+attn body: BM=64, 8 waves 2x4, fp32 x staging, Cs overlaps As
// after K-loop, softmax rows stored packed to AROW=10 (20B stride).
// =====================================================================
static __device__ __forceinline__
void pool_body(const float* __restrict__ x, const unsigned short* __restrict__ WaT,
               const float* __restrict__ ba, unsigned short* __restrict__ attn,
               int by, int t, char* smem)
{
    unsigned short* As = (unsigned short*)smem;                 // [0, 24576)
    float (*Cs)[489]   = (float(*)[489])smem;                   // [0, 31296) overlaps As
    float* ba_s        = (float*)(smem + 31296);                // [31296, 33240)

    const int l  = t & 63;
    const int w  = t >> 6;
    const int wr = w >> 2;
    const int wc = w & 3;

    if (t < NATT) ba_s[t] = ba[t] * SCALE_A;

#pragma unroll
    for (int i = 0; i < 6; ++i) {
        int f   = i * 2048 + t * 4;
        int row = f / DIMC;
        int k   = f - row * DIMC;
        int m   = by * 64 + row;
        int b   = m / NPIX;
        int r   = m - b * NPIX;
        int hh  = r / WPOOL;
        int ww  = r - hh * WPOOL;
        const float* xp = x + (((size_t)(b * NH + hh * 2)) * NWW + ww * 2) * DIMC + k;
        float4 v0 = *(const float4*)(xp);
        float4 v1 = *(const float4*)(xp + DIMC);
        float4 v2 = *(const float4*)(xp + (size_t)NWW * DIMC);
        float4 v3 = *(const float4*)(xp + (size_t)NWW * DIMC + DIMC);
        ushort4 u;
        u.x = f2bf(0.25f * (v0.x + v1.x + v2.x + v3.x));
        u.y = f2bf(0.25f * (v0.y + v1.y + v2.y + v3.y));
        u.z = f2bf(0.25f * (v0.z + v1.z + v2.z + v3.z));
        u.w = f2bf(0.25f * (v0.w + v1.w + v2.w + v3.w));
        int off = (row * 384 + k * 2) ^ ((row & 7) << 4);
        *(ushort4*)((char*)As + off) = u;
    }
    __syncthreads();

    f32x4 acc[2][8];
#pragma unroll
    for (int mi = 0; mi < 2; ++mi)
#pragma unroll
        for (int ni = 0; ni < 8; ++ni) acc[mi][ni] = (f32x4)0.f;

    const int arow0 = wr * 32 + (l & 15);
    const int kb    = (l >> 4) << 4;

#pragma unroll
    for (int ks = 0; ks < 6; ++ks) {
        bf16x8 a[2], b[8];
#pragma unroll
        for (int mi = 0; mi < 2; ++mi) {
            int row = arow0 + mi * 16;
            int off = (row * 384 + ks * 64 + kb) ^ ((row & 7) << 4);
            a[mi] = *(const bf16x8*)((const char*)As + off);
        }
#pragma unroll
        for (int ni = 0; ni < 8; ++ni) {
            int n = wc * 128 + ni * 16 + (l & 15);
            b[ni] = *(const bf16x8*)(WaT + (size_t)n * DIMC + ks * 32 + ((l >> 4) << 3));
        }
#pragma unroll
        for (int mi = 0; mi < 2; ++mi)
#pragma unroll
            for (int ni = 0; ni < 8; ++ni)
                acc[mi][ni] = __builtin_amdgcn_mfma_f32_16x16x32_bf16(
                    a[mi], b[ni], acc[mi][ni], 0, 0, 0);
    }

    __syncthreads();   // all waves done reading As before Cs overwrite

#pragma unroll
    for (int r0 = 0; r0 < 64; r0 += 16) {
        const int mi = (r0 >> 4) & 1;
        if (wr == (r0 >> 5)) {
#pragma unroll
            for (int ni = 0; ni < 8; ++ni) {
                int col = wc * 128 + ni * 16 + (l & 15);
                if (col < NATT) {
#pragma unroll
                    for (int r = 0; r < 4; ++r)
                        Cs[((l >> 4) << 2) + r][col] =
                            (mi == 0 ? acc[0][ni][r] : acc[1][ni][r]) + ba_s[col];
                }
            }
        }
        __syncthreads();
        for (int g = t; g < 864; g += 512) {
            int lr = g / 54;
            int cg = g - lr * 54;                 // head*9 + pp
            const float* ap = &Cs[lr][cg * 9];
            float mx = ap[0];
#pragma unroll
            for (int q = 1; q < 9; ++q) mx = fmaxf(mx, ap[q]);
            float e[9];
            float sum = 0.f;
#pragma unroll
            for (int q = 0; q < 9; ++q) { e[q] = __expf(ap[q] - mx); sum += e[q]; }
            float inv = 1.f / sum;
            int m = by * 64 + r0 + lr;
            unsigned short* dst = attn + ((size_t)m * 54 + cg) * AROW;   // 20B stride
            bf16x8u ov;
#pragma unroll
            for (int q = 0; q < 8; ++q) ov[q] = (short)f2bf(e[q] * inv);
            *(bf16x8u*)dst = ov;
            dst[8] = f2bf(e[8] * inv);
        }
        __syncthreads();
    }
}

// =====================================================================
// Phase 1 fused dispatch, POOL FIRST: blocks 0..195 = pool+attn,
// 196..1763 = GEMM0. smem 36.9KB -> 3 blocks/CU (VGPR 84-capped).
// =====================================================================
__global__ __launch_bounds__(512)
void phase1_kernel(const float* __restrict__ x, const unsigned short* __restrict__ WTv,
                   const unsigned short* __restrict__ WaT, const float* __restrict__ ba,
                   unsigned short* __restrict__ vp, unsigned short* __restrict__ attn)
{
    __shared__ __align__(16) char smem[36864];   // max(36864 gemm0, 33240 pool)
    const int t = threadIdx.x;
    if (blockIdx.x < 196) pool_body(x, WaT, ba, attn, blockIdx.x, t, smem);
    else                  gemm0_body(x, WTv, vp, blockIdx.x - 196, t, smem);
}

// =====================================================================
// Staging helper for gemm1: 128-row bf16 tile -> swizzled LDS async
// =====================================================================
static __device__ __forceinline__
void stage_tile_async(const unsigned short* __restrict__ Ab, unsigned short* As, int t)
{
#pragma unroll
    for (int i = 0; i < 6; ++i) {
        int L     = i * 8192 + t * 16;
        int row   = L / 384;
        int inrow = L - row * 384;
        int s     = (row & 7) << 4;
        const unsigned short* src = Ab + (size_t)row * DIMC + ((inrow ^ s) >> 1);
        gload_lds16(src, (char*)As + i * 8192 + (t >> 6) * 1024);
    }
}

// =====================================================================
// GEMM1: BM=128, 512 thr, 8 waves. XCD-aligned by = (flat&7)*49+flat>>3.
// =====================================================================
__global__ __launch_bounds__(512)
void gemm1_kernel(const unsigned short* __restrict__ Av, const unsigned short* __restrict__ WT,
                  const float* __restrict__ bias, float* __restrict__ Cv)
{
    __shared__ __align__(16) unsigned short As[128 * DIMC];   // 48 KB

    const int t  = threadIdx.x;
    const int l  = t & 63;
    const int w  = t >> 6;
    const int wr = w >> 1;
    const int wc = w & 1;
    const int flat = blockIdx.x;
    const int by   = (flat & 7) * 49 + (flat >> 3);   // bijective: 392 = 8*49

    stage_tile_async(Av + (size_t)by * 128 * DIMC, As, t);
    __syncthreads();

    f32x4 acc[2][6];
#pragma unroll
    for (int mi = 0; mi < 2; ++mi)
#pragma unroll
        for (int ni = 0; ni < 6; ++ni) acc[mi][ni] = (f32x4)0.f;

    const int arow0 = wr * 32 + (l & 15);
    const int kb    = (l >> 4) << 4;

#pragma unroll
    for (int ks = 0; ks < 6; ++ks) {
        bf16x8 a[2], b[6];
#pragma unroll
        for (int mi = 0; mi < 2; ++mi) {
            int row = arow0 + mi * 16;
            int off = (row * 384 + ks * 64 + kb) ^ ((row & 7) << 4);
            a[mi] = *(const bf16x8*)((const char*)As + off);
        }
#pragma unroll
        for (int ni = 0; ni < 6; ++ni) {
            int n = wc * 96 + ni * 16 + (l & 15);
            b[ni] = *(const bf16x8*)(WT + (size_t)n * DIMC + ks * 32 + ((l >> 4) << 3));
        }
#pragma unroll
        for (int mi = 0; mi < 2; ++mi)
#pragma unroll
            for (int ni = 0; ni < 6; ++ni)
                acc[mi][ni] = __builtin_amdgcn_mfma_f32_16x16x32_bf16(
                    a[mi], b[ni], acc[mi][ni], 0, 0, 0);
    }

    float* fAs = (float*)As;
#pragma unroll
    for (int chunk = 0; chunk < 4; ++chunk) {
        __syncthreads();
        if (wr == chunk) {
#pragma unroll
            for (int mi = 0; mi < 2; ++mi) {
#pragma unroll
                for (int r = 0; r < 4; ++r) {
                    int rowl = mi * 16 + ((l >> 4) << 2) + r;
#pragma unroll
                    for (int ni = 0; ni < 6; ++ni) {
                        int col = wc * 96 + ni * 16 + (l & 15);
                        fAs[rowl * DIMC + col] = acc[mi][ni][r];
                    }
                }
            }
        }
        __syncthreads();
#pragma unroll
        for (int i = 0; i < 3; ++i) {
            int f   = i * 2048 + t * 4;
            int row = f / DIMC;
            int k   = f - row * DIMC;
            int m   = by * 128 + chunk * 32 + row;
            float4 v  = *(const float4*)&fAs[f];
            float4 bv = *(const float4*)&bias[k];
            v.x += bv.x; v.y += bv.y; v.z += bv.z; v.w += bv.w;
            *(float4*)(Cv + (size_t)m * DIMC + k) = v;
        }
    }
}

// =====================================================================
// Gather (R19-proven): 25088 blocks, 2 same-parity pixels x 96 thr x
// 2 ch, batched loads, packed attn rows, XCD batch sweep.
// =====================================================================
template<int NI, int NJ>
static __device__ __forceinline__ void gather_body(
    int b, int p, int qc, int head, int c,
    const unsigned short* __restrict__ attn, const unsigned short* __restrict__ vp,
    unsigned short* __restrict__ y)
{
    const int pr = p >> 1;
    const int qr = qc >> 1;

    bf16x8u       aw8[NI * NJ];
    unsigned short aw9[NI * NJ];
    ushort2       v[NI * NJ][9];
    bool          ok[NI * NJ];

#pragma unroll
    for (int wi = 0; wi < NI; ++wi) {
        const bool hv  = (NI == 1) || (wi == 0) || (pr + 1 < HPOOL);
        const int  hhs = hv ? (pr + wi) : (HPOOL - 1);
        const int  iof = (NI == 1) ? 1 : (wi ? 0 : 2);
#pragma unroll
        for (int wj = 0; wj < NJ; ++wj) {
            const bool wv  = (NJ == 1) || (wj == 0) || (qr + 1 < WPOOL);
            const int  wws = wv ? (qr + wj) : (WPOOL - 1);
            const int  jof = (NJ == 1) ? 1 : (wj ? 0 : 2);
            const int  idx = wi * NJ + wj;
            ok[idx] = hv && wv;

            const unsigned short* ap = attn +
                ((size_t)((b * NPIX + hhs * WPOOL + wws) * 54 + head * 9 + iof * 3 + jof)) * AROW;
            aw8[idx] = *(const bf16x8u*)ap;
            aw9[idx] = ap[8];

            const unsigned short* vb = vp +
                (((size_t)(b * VH + 2 * hhs)) * VW + 2 * wws) * DIMC + c;
#pragma unroll
            for (int qi = 0; qi < 3; ++qi)
#pragma unroll
                for (int qj = 0; qj < 3; ++qj)
                    v[idx][qi * 3 + qj] = *(const ushort2*)(vb + ((size_t)qi * VW + qj) * DIMC);
        }
    }

    float accx = 0.f, accy = 0.f;
#pragma unroll
    for (int idx = 0; idx < NI * NJ; ++idx) {
#pragma unroll
        for (int k = 0; k < 9; ++k) {
            float a = ok[idx]
                ? ((k < 8) ? bf2f((unsigned short)aw8[idx][k]) : bf2f(aw9[idx]))
                : 0.f;
            accx = fmaf(a, bf2f(v[idx][k].x), accx);
            accy = fmaf(a, bf2f(v[idx][k].y), accy);
        }
    }

    size_t pix = (size_t)b * (NH * NWW) + (size_t)p * NWW + qc;
    ushort2 r;
    r.x = f2bf(accx);
    r.y = f2bf(accy);
    *(ushort2*)(y + pix * DIMC + c) = r;
}

__global__ __launch_bounds__(192)
void gather_kernel(const unsigned short* __restrict__ attn,
                   const unsigned short* __restrict__ vp,
                   unsigned short* __restrict__ y)
{
    const int t    = threadIdx.x;
    const int pl   = t / 96;
    const int c2   = t - pl * 96;
    const int c    = c2 * 2;
    const int head = c2 >> 4;

    const int flat = blockIdx.x;
    const int wgid = (flat & 7) * 3136 + (flat >> 3);
    const int b    = wgid / 1568;
    const int rr   = wgid - b * 1568;
    const int p    = rr / 28;
    const int wq   = rr - p * 28;
    const int qc   = wq + pl * 28;

    if (p & 1) {
        if (wq & 1) gather_body<2, 2>(b, p, qc, head, c, attn, vp, y);
        else        gather_body<2, 1>(b, p, qc, head, c, attn, vp, y);
    } else {
        if (wq & 1) gather_body<1, 2>(b, p, qc, head, c, attn, vp, y);
        else        gather_body<1, 1>(b, p, qc, head, c, attn, vp, y);
    }
}

// =====================================================================
extern "C" void kernel_launch(void* const* d_in, const int* in_sizes, int n_in,
                              void* d_out, int out_size, void* d_ws, size_t ws_size,
                              hipStream_t stream)
{
    const float* x  = (const float*)d_in[0];
    const float* Wv = (const float*)d_in[1];
    const float* Wa = (const float*)d_in[2];
    const float* ba = (const float*)d_in[3];
    const float* Wp = (const float*)d_in[4];
    const float* bp = (const float*)d_in[5];
    float* out = (float*)d_out;

    const size_t vp_elems   = (size_t)NB * VH * VW * DIMC;   // bf16
    const size_t attn_elems = (size_t)MPOOL * 54 * AROW + 8; // bf16, packed rows
    const size_t y_elems    = (size_t)MROWS * DIMC;          // bf16

    unsigned short* vp   = (unsigned short*)d_ws;
    unsigned short* attn = vp + vp_elems;
    unsigned short* y    = attn + attn_elems;
    unsigned short* WTv  = y + y_elems;
    unsigned short* WTp  = WTv + 36864;
    unsigned short* WaT  = WTp + 36864;

    prep_kernel<<<2040, 256, 0, stream>>>(Wv, Wp, Wa, WTv, WTp, WaT, (unsigned int*)vp);

    // 196 pool blocks first (longest-job-first), then 1568 gemm0 blocks
    phase1_kernel<<<1764, 512, 0, stream>>>(x, WTv, WaT, ba, vp, attn);

    gather_kernel<<<25088, 192, 0, stream>>>(attn, vp, y);

    gemm1_kernel<<<392, 512, 0, stream>>>(y, WTp, bp, out);
}

// Round 24
// 102.262 us; speedup vs baseline: 1.1351x; 1.1351x over previous
//
#include <hip/hip_runtime.h>
#include <cstdint>
#include <cstddef>

#define DIMC    192
#define NHEADS  6
#define NATT    486
#define NB      16
#define NH      56
#define NWW     56
#define HPOOL   28
#define WPOOL   28
#define NPIX    784
#define VH      58
#define VW      58
#define MROWS   (NB*NH*NWW)      // 50176
#define MPOOL   (NB*NPIX)        // 12544
#define SCALE_A 0.17677669529663687f
#define AROW    10               // attn row stride (bf16 elems): 9 weights + 1 pad

using bf16x8 = __attribute__((ext_vector_type(8))) short;
using f32x4  = __attribute__((ext_vector_type(4))) float;
typedef short bf16x8u __attribute__((vector_size(16), aligned(4)));   // 16B load @4B align

static __device__ __forceinline__ unsigned short f2bf(float f) {
    unsigned int u = __float_as_uint(f);
    unsigned int r = (u + 0x7fffu + ((u >> 16) & 1u)) >> 16;   // RNE
    return (unsigned short)r;
}
static __device__ __forceinline__ float bf2f(unsigned short u) {
    return __uint_as_float((unsigned int)u << 16);
}

// async global->LDS, 16B per lane
static __device__ __forceinline__ void gload_lds16(const void* src, void* lds) {
    __builtin_amdgcn_global_load_lds(
        (const __attribute__((address_space(1))) void*)src,
        (__attribute__((address_space(3))) void*)lds, 16, 0, 0);
}

// =====================================================================
// Prep: WTv/WTp[n][k]=bf16(W[k][n]); WaT=bf16(Wa*SCALE); vp border=0.
// =====================================================================
__global__ __launch_bounds__(256)
void prep_kernel(const float* __restrict__ Wv, const float* __restrict__ Wp,
                 const float* __restrict__ Wa,
                 unsigned short* __restrict__ WTv, unsigned short* __restrict__ WTp,
                 unsigned short* __restrict__ WaT, unsigned int* __restrict__ vpu)
{
    int idx = blockIdx.x * 256 + threadIdx.x;
    if (idx < 73728) {
        int sel = idx / 36864;
        int r   = idx - sel * 36864;
        int n   = r / DIMC;
        int k   = r - n * DIMC;
        const float* W = sel ? Wp : Wv;
        unsigned short* WT = sel ? WTp : WTv;
        WT[r] = f2bf(W[k * DIMC + n]);
    } else if (idx < 172032) {
        int r = idx - 73728;
        int n = r / DIMC;
        int k = r - n * DIMC;
        WaT[r] = (n < NATT) ? f2bf(Wa[(size_t)k * NATT + n] * SCALE_A) : (unsigned short)0;
    } else {
        int i2   = idx - 172032;                  // 0..350207
        int cu   = i2 % 96;
        int rest = i2 / 96;
        int b    = rest / 228;
        int p    = rest - b * 228;
        int hi, wi;
        if (p < 58)       { hi = 0;  wi = p; }
        else if (p < 116) { hi = 57; wi = p - 58; }
        else { int q = p - 116; hi = 1 + (q >> 1); wi = (q & 1) * 57; }
        vpu[(((size_t)b * VH + hi) * VW + wi) * 96 + cu] = 0u;
    }
}

// =====================================================================
// GEMM0 body (R21/R22-proven): BM=64, half-N (96 cols), 512 thr, 8 waves.
// Staged A (fp32->bf16 swizzled LDS) + Ws via pre-swizzled gload_lds.
// XCD+batch-aligned mapping: xcd=(g+4)&7, rank=g>>3,
// tile=xcd*98+(rank>>1), half=rank&1 -> halves on same XCD (x L2-hot),
// XCD i produces vp for batches 2i,2i+1.
// =====================================================================
static __device__ __forceinline__
void gemm0_body(const float* __restrict__ x, const unsigned short* __restrict__ WTv,
                unsigned short* __restrict__ vp, int g, int t, char* smem)
{
    unsigned short* As = (unsigned short*)smem;            // [0, 24576)
    unsigned short* Ws = (unsigned short*)(smem + 24576);  // [24576, 61440)

    const int xcd  = (g + 4) & 7;
    const int rank = g >> 3;               // 0..195 within this XCD
    const int tile = xcd * 98 + (rank >> 1);   // 0..783
    const int half = rank & 1;
    const int l  = t & 63;
    const int w  = t >> 6;
    const int wr = w >> 1;          // 0..3 : 16-row band
    const int wc = w & 1;           // 0..1 : 48-col half of the 96

    // ---- stage Ws: 96 WT rows (bf16) -> swizzled LDS, async ----
    const unsigned short* Wb = WTv + (size_t)half * 96 * DIMC;
#pragma unroll
    for (int i = 0; i < 5; ++i) {
        int L = i * 8192 + t * 16;
        if (L < 36864) {
            int row   = L / 384;
            int inrow = L - row * 384;
            int s     = (row & 7) << 4;
            const unsigned short* src = Wb + (size_t)row * DIMC + ((inrow ^ s) >> 1);
            gload_lds16(src, (char*)Ws + (L & ~1023) + ((t & 63) << 4));
        }
    }

    // ---- stage As: 64 rows fp32 -> bf16 swizzled ----
    const float* Ab = x + (size_t)tile * 64 * DIMC;
#pragma unroll
    for (int i = 0; i < 6; ++i) {
        int f   = i * 2048 + t * 4;           // element idx in [0,12288)
        float4 v = *(const float4*)(Ab + f);
        int row = f / DIMC;
        int k   = f - row * DIMC;
        ushort4 u;
        u.x = f2bf(v.x); u.y = f2bf(v.y); u.z = f2bf(v.z); u.w = f2bf(v.w);
        int off = (row * 384 + k * 2) ^ ((row & 7) << 4);
        *(ushort4*)((char*)As + off) = u;
    }
    __syncthreads();   // drains vmcnt (Ws) + lds writes (As)

    f32x4 acc[3];
#pragma unroll
    for (int ni = 0; ni < 3; ++ni) acc[ni] = (f32x4)0.f;

    const int arow = wr * 16 + (l & 15);
    const int kb   = (l >> 4) << 4;
    const int aswz = (arow & 7) << 4;

#pragma unroll
    for (int ks = 0; ks < 6; ++ks) {
        bf16x8 a = *(const bf16x8*)((const char*)As +
                        ((arow * 384 + ks * 64 + kb) ^ aswz));
        bf16x8 b[3];
#pragma unroll
        for (int ni = 0; ni < 3; ++ni) {
            int n = wc * 48 + ni * 16 + (l & 15);
            b[ni] = *(const bf16x8*)((const char*)Ws +
                        ((n * 384 + ks * 64 + kb) ^ ((n & 7) << 4)));
        }
#pragma unroll
        for (int ni = 0; ni < 3; ++ni)
            acc[ni] = __builtin_amdgcn_mfma_f32_16x16x32_bf16(a, b[ni], acc[ni], 0, 0, 0);
    }

    // ---- epilogue: 64x96 bf16 half-tile via LDS (reuse As region) ----
    __syncthreads();
    unsigned short* Cs = As;                   // [64][96] = 12 KB
#pragma unroll
    for (int ni = 0; ni < 3; ++ni) {
        int col = wc * 48 + ni * 16 + (l & 15);
#pragma unroll
        for (int r = 0; r < 4; ++r) {
            int row = wr * 16 + ((l >> 4) << 2) + r;
            Cs[row * 96 + col] = f2bf(acc[ni][r]);
        }
    }
    __syncthreads();
#pragma unroll
    for (int i = 0; i < 2; ++i) {
        int idx = i * 8192 + t * 16;           // byte offset in [0,12288)
        if (idx < 12288) {
            int row = idx / 192;
            int cb  = idx - row * 192;         // byte within row (96 cols * 2B)
            int m   = tile * 64 + row;
            int bb  = m / (NH * NWW);
            int rr  = m - bb * (NH * NWW);
            int hi  = rr / NWW;
            int wi  = rr - hi * NWW;
            bf16x8 v = *(const bf16x8*)((const char*)Cs + idx);
            unsigned short* dst = vp +
                (((size_t)bb * VH + hi + 1) * VW + (wi + 1)) * DIMC + half * 96 + (cb >> 1);
            *(bf16x8*)dst = v;
        }
    }
}

// =====================================================================
// pool+attn body: BM=64, 8 waves 2x4, fp32 x staging, Cs overlaps As
// after K-loop, softmax rows stored packed to AROW=10 (20B stride).
// =====================================================================
static __device__ __forceinline__
void pool_body(const float* __restrict__ x, const unsigned short* __restrict__ WaT,
               const float* __restrict__ ba, unsigned short* __restrict__ attn,
               int by, int t, char* smem)
{
    unsigned short* As = (unsigned short*)smem;                 // [0, 24576)
    float (*Cs)[489]   = (float(*)[489])smem;                   // [0, 31296) overlaps As
    float* ba_s        = (float*)(smem + 31296);                // [31296, 33240)

    const int l  = t & 63;
    const int w  = t >> 6;
    const int wr = w >> 2;
    const int wc = w & 3;

    if (t < NATT) ba_s[t] = ba[t] * SCALE_A;

#pragma unroll
    for (int i = 0; i < 6; ++i) {
        int f   = i * 2048 + t * 4;
        int row = f / DIMC;
        int k   = f - row * DIMC;
        int m   = by * 64 + row;
        int b   = m / NPIX;
        int r   = m - b * NPIX;
        int hh  = r / WPOOL;
        int ww  = r - hh * WPOOL;
        const float* xp = x + (((size_t)(b * NH + hh * 2)) * NWW + ww * 2) * DIMC + k;
        float4 v0 = *(const float4*)(xp);
        float4 v1 = *(const float4*)(xp + DIMC);
        float4 v2 = *(const float4*)(xp + (size_t)NWW * DIMC);
        float4 v3 = *(const float4*)(xp + (size_t)NWW * DIMC + DIMC);
        ushort4 u;
        u.x = f2bf(0.25f * (v0.x + v1.x + v2.x + v3.x));
        u.y = f2bf(0.25f * (v0.y + v1.y + v2.y + v3.y));
        u.z = f2bf(0.25f * (v0.z + v1.z + v2.z + v3.z));
        u.w = f2bf(0.25f * (v0.w + v1.w + v2.w + v3.w));
        int off = (row * 384 + k * 2) ^ ((row & 7) << 4);
        *(ushort4*)((char*)As + off) = u;
    }
    __syncthreads();

    f32x4 acc[2][8];
#pragma unroll
    for (int mi = 0; mi < 2; ++mi)
#pragma unroll
        for (int ni = 0; ni < 8; ++ni) acc[mi][ni] = (f32x4)0.f;

    const int arow0 = wr * 32 + (l & 15);
    const int kb    = (l >> 4) << 4;

#pragma unroll
    for (int ks = 0; ks < 6; ++ks) {
        bf16x8 a[2], b[8];
#pragma unroll
        for (int mi = 0; mi < 2; ++mi) {
            int row = arow0 + mi * 16;
            int off = (row * 384 + ks * 64 + kb) ^ ((row & 7) << 4);
            a[mi] = *(const bf16x8*)((const char*)As + off);
        }
#pragma unroll
        for (int ni = 0; ni < 8; ++ni) {
            int n = wc * 128 + ni * 16 + (l & 15);
            b[ni] = *(const bf16x8*)(WaT + (size_t)n * DIMC + ks * 32 + ((l >> 4) << 3));
        }
#pragma unroll
        for (int mi = 0; mi < 2; ++mi)
#pragma unroll
            for (int ni = 0; ni < 8; ++ni)
                acc[mi][ni] = __builtin_amdgcn_mfma_f32_16x16x32_bf16(
                    a[mi], b[ni], acc[mi][ni], 0, 0, 0);
    }

    __syncthreads();   // all waves done reading As before Cs overwrite

#pragma unroll
    for (int r0 = 0; r0 < 64; r0 += 16) {
        const int mi = (r0 >> 4) & 1;
        if (wr == (r0 >> 5)) {
#pragma unroll
            for (int ni = 0; ni < 8; ++ni) {
                int col = wc * 128 + ni * 16 + (l & 15);
                if (col < NATT) {
#pragma unroll
                    for (int r = 0; r < 4; ++r)
                        Cs[((l >> 4) << 2) + r][col] =
                            (mi == 0 ? acc[0][ni][r] : acc[1][ni][r]) + ba_s[col];
                }
            }
        }
        __syncthreads();
        for (int g = t; g < 864; g += 512) {
            int lr = g / 54;
            int cg = g - lr * 54;                 // head*9 + pp
            const float* ap = &Cs[lr][cg * 9];
            float mx = ap[0];
#pragma unroll
            for (int q = 1; q < 9; ++q) mx = fmaxf(mx, ap[q]);
            float e[9];
            float sum = 0.f;
#pragma unroll
            for (int q = 0; q < 9; ++q) { e[q] = __expf(ap[q] - mx); sum += e[q]; }
            float inv = 1.f / sum;
            int m = by * 64 + r0 + lr;
            unsigned short* dst = attn + ((size_t)m * 54 + cg) * AROW;   // 20B stride
            bf16x8u ov;
#pragma unroll
            for (int q = 0; q < 8; ++q) ov[q] = (short)f2bf(e[q] * inv);
            *(bf16x8u*)dst = ov;
            dst[8] = f2bf(e[8] * inv);
        }
        __syncthreads();
    }
}

// =====================================================================
// Phase 1 fused dispatch, POOL FIRST: blocks 0..195 = pool+attn,
// 196..1763 = GEMM0 (XCD+batch-aligned mapping). smem 60KB -> 2/CU.
// =====================================================================
__global__ __launch_bounds__(512)
void phase1_kernel(const float* __restrict__ x, const unsigned short* __restrict__ WTv,
                   const unsigned short* __restrict__ WaT, const float* __restrict__ ba,
                   unsigned short* __restrict__ vp, unsigned short* __restrict__ attn)
{
    __shared__ __align__(16) char smem[61440];   // 60 KB
    const int t = threadIdx.x;
    if (blockIdx.x < 196) pool_body(x, WaT, ba, attn, blockIdx.x, t, smem);
    else                  gemm0_body(x, WTv, vp, blockIdx.x - 196, t, smem);
}

// =====================================================================
// Staging helper for gemm1: 128-row bf16 tile -> swizzled LDS async
// =====================================================================
static __device__ __forceinline__
void stage_tile_async(const unsigned short* __restrict__ Ab, unsigned short* As, int t)
{
#pragma unroll
    for (int i = 0; i < 6; ++i) {
        int L     = i * 8192 + t * 16;
        int row   = L / 384;
        int inrow = L - row * 384;
        int s     = (row & 7) << 4;
        const unsigned short* src = Ab + (size_t)row * DIMC + ((inrow ^ s) >> 1);
        gload_lds16(src, (char*)As + i * 8192 + (t >> 6) * 1024);
    }
}

// =====================================================================
// GEMM1: BM=128, 512 thr, 8 waves. XCD-aligned by = (flat&7)*49+flat>>3.
// =====================================================================
__global__ __launch_bounds__(512)
void gemm1_kernel(const unsigned short* __restrict__ Av, const unsigned short* __restrict__ WT,
                  const float* __restrict__ bias, float* __restrict__ Cv)
{
    __shared__ __align__(16) unsigned short As[128 * DIMC];   // 48 KB

    const int t  = threadIdx.x;
    const int l  = t & 63;
    const int w  = t >> 6;
    const int wr = w >> 1;
    const int wc = w & 1;
    const int flat = blockIdx.x;
    const int by   = (flat & 7) * 49 + (flat >> 3);   // bijective: 392 = 8*49

    stage_tile_async(Av + (size_t)by * 128 * DIMC, As, t);
    __syncthreads();

    f32x4 acc[2][6];
#pragma unroll
    for (int mi = 0; mi < 2; ++mi)
#pragma unroll
        for (int ni = 0; ni < 6; ++ni) acc[mi][ni] = (f32x4)0.f;

    const int arow0 = wr * 32 + (l & 15);
    const int kb    = (l >> 4) << 4;

#pragma unroll
    for (int ks = 0; ks < 6; ++ks) {
        bf16x8 a[2], b[6];
#pragma unroll
        for (int mi = 0; mi < 2; ++mi) {
            int row = arow0 + mi * 16;
            int off = (row * 384 + ks * 64 + kb) ^ ((row & 7) << 4);
            a[mi] = *(const bf16x8*)((const char*)As + off);
        }
#pragma unroll
        for (int ni = 0; ni < 6; ++ni) {
            int n = wc * 96 + ni * 16 + (l & 15);
            b[ni] = *(const bf16x8*)(WT + (size_t)n * DIMC + ks * 32 + ((l >> 4) << 3));
        }
#pragma unroll
        for (int mi = 0; mi < 2; ++mi)
#pragma unroll
            for (int ni = 0; ni < 6; ++ni)
                acc[mi][ni] = __builtin_amdgcn_mfma_f32_16x16x32_bf16(
                    a[mi], b[ni], acc[mi][ni], 0, 0, 0);
    }

    float* fAs = (float*)As;
#pragma unroll
    for (int chunk = 0; chunk < 4; ++chunk) {
        __syncthreads();
        if (wr == chunk) {
#pragma unroll
            for (int mi = 0; mi < 2; ++mi) {
#pragma unroll
                for (int r = 0; r < 4; ++r) {
                    int rowl = mi * 16 + ((l >> 4) << 2) + r;
#pragma unroll
                    for (int ni = 0; ni < 6; ++ni) {
                        int col = wc * 96 + ni * 16 + (l & 15);
                        fAs[rowl * DIMC + col] = acc[mi][ni][r];
                    }
                }
            }
        }
        __syncthreads();
#pragma unroll
        for (int i = 0; i < 3; ++i) {
            int f   = i * 2048 + t * 4;
            int row = f / DIMC;
            int k   = f - row * DIMC;
            int m   = by * 128 + chunk * 32 + row;
            float4 v  = *(const float4*)&fAs[f];
            float4 bv = *(const float4*)&bias[k];
            v.x += bv.x; v.y += bv.y; v.z += bv.z; v.w += bv.w;
            *(float4*)(Cv + (size_t)m * DIMC + k) = v;
        }
    }
}

// =====================================================================
// Gather (R19-proven): 25088 blocks, 2 same-parity pixels x 96 thr x
// 2 ch, batched loads, packed attn rows, XCD batch sweep.
// =====================================================================
template<int NI, int NJ>
static __device__ __forceinline__ void gather_body(
    int b, int p, int qc, int head, int c,
    const unsigned short* __restrict__ attn, const unsigned short* __restrict__ vp,
    unsigned short* __restrict__ y)
{
    const int pr = p >> 1;
    const int qr = qc >> 1;

    bf16x8u       aw8[NI * NJ];
    unsigned short aw9[NI * NJ];
    ushort2       v[NI * NJ][9];
    bool          ok[NI * NJ];

#pragma unroll
    for (int wi = 0; wi < NI; ++wi) {
        const bool hv  = (NI == 1) || (wi == 0) || (pr + 1 < HPOOL);
        const int  hhs = hv ? (pr + wi) : (HPOOL - 1);
        const int  iof = (NI == 1) ? 1 : (wi ? 0 : 2);
#pragma unroll
        for (int wj = 0; wj < NJ; ++wj) {
            const bool wv  = (NJ == 1) || (wj == 0) || (qr + 1 < WPOOL);
            const int  wws = wv ? (qr + wj) : (WPOOL - 1);
            const int  jof = (NJ == 1) ? 1 : (wj ? 0 : 2);
            const int  idx = wi * NJ + wj;
            ok[idx] = hv && wv;

            const unsigned short* ap = attn +
                ((size_t)((b * NPIX + hhs * WPOOL + wws) * 54 + head * 9 + iof * 3 + jof)) * AROW;
            aw8[idx] = *(const bf16x8u*)ap;
            aw9[idx] = ap[8];

            const unsigned short* vb = vp +
                (((size_t)(b * VH + 2 * hhs)) * VW + 2 * wws) * DIMC + c;
#pragma unroll
            for (int qi = 0; qi < 3; ++qi)
#pragma unroll
                for (int qj = 0; qj < 3; ++qj)
                    v[idx][qi * 3 + qj] = *(const ushort2*)(vb + ((size_t)qi * VW + qj) * DIMC);
        }
    }

    float accx = 0.f, accy = 0.f;
#pragma unroll
    for (int idx = 0; idx < NI * NJ; ++idx) {
#pragma unroll
        for (int k = 0; k < 9; ++k) {
            float a = ok[idx]
                ? ((k < 8) ? bf2f((unsigned short)aw8[idx][k]) : bf2f(aw9[idx]))
                : 0.f;
            accx = fmaf(a, bf2f(v[idx][k].x), accx);
            accy = fmaf(a, bf2f(v[idx][k].y), accy);
        }
    }

    size_t pix = (size_t)b * (NH * NWW) + (size_t)p * NWW + qc;
    ushort2 r;
    r.x = f2bf(accx);
    r.y = f2bf(accy);
    *(ushort2*)(y + pix * DIMC + c) = r;
}

__global__ __launch_bounds__(192)
void gather_kernel(const unsigned short* __restrict__ attn,
                   const unsigned short* __restrict__ vp,
                   unsigned short* __restrict__ y)
{
    const int t    = threadIdx.x;
    const int pl   = t / 96;
    const int c2   = t - pl * 96;
    const int c    = c2 * 2;
    const int head = c2 >> 4;

    const int flat = blockIdx.x;
    const int wgid = (flat & 7) * 3136 + (flat >> 3);
    const int b    = wgid / 1568;
    const int rr   = wgid - b * 1568;
    const int p    = rr / 28;
    const int wq   = rr - p * 28;
    const int qc   = wq + pl * 28;

    if (p & 1) {
        if (wq & 1) gather_body<2, 2>(b, p, qc, head, c, attn, vp, y);
        else        gather_body<2, 1>(b, p, qc, head, c, attn, vp, y);
    } else {
        if (wq & 1) gather_body<1, 2>(b, p, qc, head, c, attn, vp, y);
        else        gather_body<1, 1>(b, p, qc, head, c, attn, vp, y);
    }
}

// =====================================================================
extern "C" void kernel_launch(void* const* d_in, const int* in_sizes, int n_in,
                              void* d_out, int out_size, void* d_ws, size_t ws_size,
                              hipStream_t stream)
{
    const float* x  = (const float*)d_in[0];
    const float* Wv = (const float*)d_in[1];
    const float* Wa = (const float*)d_in[2];
    const float* ba = (const float*)d_in[3];
    const float* Wp = (const float*)d_in[4];
    const float* bp = (const float*)d_in[5];
    float* out = (float*)d_out;

    const size_t vp_elems   = (size_t)NB * VH * VW * DIMC;   // bf16
    const size_t attn_elems = (size_t)MPOOL * 54 * AROW + 8; // bf16, packed rows
    const size_t y_elems    = (size_t)MROWS * DIMC;          // bf16

    unsigned short* vp   = (unsigned short*)d_ws;
    unsigned short* attn = vp + vp_elems;
    unsigned short* y    = attn + attn_elems;
    unsigned short* WTv  = y + y_elems;
    unsigned short* WTp  = WTv + 36864;
    unsigned short* WaT  = WTp + 36864;

    prep_kernel<<<2040, 256, 0, stream>>>(Wv, Wp, Wa, WTv, WTp, WaT, (unsigned int*)vp);

    // 196 pool blocks first (longest-job-first), then 1568 gemm0 blocks
    phase1_kernel<<<1764, 512, 0, stream>>>(x, WTv, WaT, ba, vp, attn);

    gather_kernel<<<25088, 192, 0, stream>>>(attn, vp, y);

    gemm1_kernel<<<392, 512, 0, stream>>>(y, WTp, bp, out);
}